// Round 15
// baseline (524.773 us; speedup 1.0000x reference)
//
#include <hip/hip_runtime.h>

typedef unsigned short u16;
typedef unsigned int   u32;
typedef __bf16 bf16x8 __attribute__((ext_vector_type(8)));
typedef float  f32x16 __attribute__((ext_vector_type(16)));

__device__ __forceinline__ u16 f2bf(float f){
  u32 u = __float_as_uint(f);
  u32 r = (u + 0x7FFFu + ((u >> 16) & 1u)) >> 16;   // RNE
  return (u16)r;
}

#define GLD(dst, p, OFF) \
  asm volatile("global_load_dwordx4 %0, %1, off offset:" OFF \
               : "=&v"(dst) : "v"(p))
#define WAITV(N) do { \
    asm volatile("s_waitcnt vmcnt(" N ")"); \
    __builtin_amdgcn_sched_barrier(0); \
  } while (0)

// ===========================================================================
// R15 = INSTRUMENTATION ROUND. R14's kernel + 3 extra (idempotent) launches
// of layer-2's gemm_rt. T_gemm256 = (total - 380.9)/3. Five structural gemm
// experiments were null; per-kernel visibility is gone (harness poison fills
// occupy the top-5); this buys back the critical number. R16 reverts.
// ===========================================================================

// ---------------------------------------------------------------------------
// Pass 1: row sums + f32->bf16 + transpose to tiled layout via LDS.
// ---------------------------------------------------------------------------
__global__ __launch_bounds__(1024) void rowsum_tileA(
    const float* __restrict__ A, u16* __restrict__ Ab, float* __restrict__ ds){
  __shared__ u16 lt[8192];               // 16 tiles x 512 u16 = 16 KB
  const int t = threadIdx.x;
  const int r = t >> 5, q = t & 31;      // row 0..31, 32 threads/row
  const int rg = blockIdx.x;
  const float* ar = A + ((size_t)rg * 32 + r) * 8192;
  float s = 0.f;
  for (int ch = 0; ch < 32; ++ch){
    #pragma unroll
    for (int j = 0; j < 2; ++j){
      const int c4 = ch * 64 + j * 32 + q;           // float4 col index
      float4 v = ((const float4*)ar)[c4];
      s += (v.x + v.y) + (v.z + v.w);
      const int cl = (j * 32 + q) * 4;               // local col 0..255
      const int idx = (cl >> 4) * 512 + ((r | (((cl >> 3) & 1) << 5)) * 8) + (cl & 7);
      ushort4 o;
      o.x = f2bf(v.x); o.y = f2bf(v.y); o.z = f2bf(v.z); o.w = f2bf(v.w);
      *(ushort4*)(lt + idx) = o;
    }
    __syncthreads();
    uint4* dst = (uint4*)(Ab + ((size_t)rg * 512 + ch * 16) * 512);
    dst[t] = ((const uint4*)lt)[t];                  // linear 16KB, coalesced
    __syncthreads();
  }
  #pragma unroll
  for (int m = 16; m > 0; m >>= 1) s += __shfl_xor(s, m, 64);
  if (q == 0) ds[rg * 32 + r] = rsqrtf(s);
}

// ---------------------------------------------------------------------------
// Small feature GEMM: Vt tiles = bf16( ds[i] * sum_k in[i][k] * W[k][o] )
// ---------------------------------------------------------------------------
template<int K, int F, bool INBF16>
__global__ __launch_bounds__(256) void small_gemm(
    const void* __restrict__ inp, const float* __restrict__ W,
    const float* __restrict__ ds, u16* __restrict__ Vt){
  constexpr int G   = 256 / F;     // 1 (F=256) or 2 (F=128)
  constexpr int RPB = 16 * G;      // rows per block
  __shared__ float xs[RPB * K];
  const int t  = threadIdx.x;
  const int r0 = blockIdx.x * RPB;
  if constexpr (INBF16){
    const u16* ip = (const u16*)inp + (size_t)r0 * K;
    constexpr int IT = (RPB * K) / (256 * 8);
    #pragma unroll
    for (int j = 0; j < IT; ++j){
      int c = j * 256 + t;
      uint4 v = ((const uint4*)ip)[c];
      float* xp = xs + c * 8;
      xp[0] = __uint_as_float((v.x & 0xFFFFu) << 16);
      xp[1] = __uint_as_float(v.x & 0xFFFF0000u);
      xp[2] = __uint_as_float((v.y & 0xFFFFu) << 16);
      xp[3] = __uint_as_float(v.y & 0xFFFF0000u);
      xp[4] = __uint_as_float((v.z & 0xFFFFu) << 16);
      xp[5] = __uint_as_float(v.z & 0xFFFF0000u);
      xp[6] = __uint_as_float((v.w & 0xFFFFu) << 16);
      xp[7] = __uint_as_float(v.w & 0xFFFF0000u);
    }
  } else {
    const float* ip = (const float*)inp + (size_t)r0 * K;
    constexpr int IT = (RPB * K) / (256 * 4);
    #pragma unroll
    for (int j = 0; j < IT; ++j){
      int c = j * 256 + t;
      ((float4*)xs)[c] = ((const float4*)ip)[c];
    }
  }
  __syncthreads();
  const int o = t % F, g = t / F;
  float acc[16];
  #pragma unroll
  for (int r = 0; r < 16; ++r) acc[r] = 0.f;
  const float* xr = xs + g * 16 * K;
  for (int k = 0; k < K; k += 4){
    float w0 = W[(k+0)*F + o];
    float w1 = W[(k+1)*F + o];
    float w2 = W[(k+2)*F + o];
    float w3 = W[(k+3)*F + o];
    #pragma unroll
    for (int r = 0; r < 16; ++r){
      float4 xv = *(const float4*)(xr + r*K + k);
      acc[r] += xv.x*w0 + xv.y*w1 + xv.z*w2 + xv.w*w3;
    }
  }
  const int rb = r0 + g * 16;              // 16-aligned -> one k-tile
  union { u16 u[16]; uint4 v[2]; } pk;
  #pragma unroll
  for (int r = 0; r < 16; ++r) pk.u[r] = f2bf(acc[r] * ds[rb + r]);
  const size_t tile = ((size_t)(o >> 5) * 512 + (rb >> 4)) * 512;
  uint4* dst = (uint4*)(Vt + tile + (size_t)(o & 31) * 8);
  dst[0]  = pk.v[0];
  dst[32] = pk.v[1];
}

// ---------------------------------------------------------------------------
// F=256 big GEMM, register-tiled wave-K-split LDS (R14).
// ---------------------------------------------------------------------------
__global__ __launch_bounds__(256) void gemm_rt(
    const u16* __restrict__ Ab, const u16* __restrict__ Vt,
    const float* __restrict__ ds, u16* __restrict__ Hout){
  __shared__ u16 Ls[2][32 * 512];        // 2 x 32KB
  const int t = threadIdx.x, w = t >> 6, lane = t & 63;
  const int rowg = blockIdx.x & 127;
  const int colg = blockIdx.x >> 7;      // 0..3

  const u16* sP0 = Ab + ((size_t)(rowg * 2 + 0) * 512) * 512 + lane * 8;
  const u16* sP1 = Ab + ((size_t)(rowg * 2 + 1) * 512) * 512 + lane * 8;
  const u16* sP2 = Vt + ((size_t)(colg * 2 + 0) * 512) * 512 + lane * 8;
  const u16* sP3 = Vt + ((size_t)(colg * 2 + 1) * 512) * 512 + lane * 8;

  f32x16 a00, a01, a10, a11;
  #pragma unroll
  for (int i = 0; i < 16; ++i){ a00[i]=0.f; a01[i]=0.f; a10[i]=0.f; a11[i]=0.f; }

  auto stage = [&](int buf, int c){
    u16* L = &Ls[buf][0] + lane * 8;
    #pragma unroll
    for (int h = 0; h < 2; ++h){
      const int kt = c * 8 + h * 4 + w;         // global k-tile
      const int sl = h * 4 + w;                 // local slot 0..7
      const size_t so = (size_t)kt * 512;
      __builtin_amdgcn_global_load_lds(
        (const __attribute__((address_space(1))) u32*)(sP0 + so),
        (__attribute__((address_space(3))) u32*)(L + (0  + sl) * 512), 16, 0, 0);
      __builtin_amdgcn_global_load_lds(
        (const __attribute__((address_space(1))) u32*)(sP1 + so),
        (__attribute__((address_space(3))) u32*)(L + (8  + sl) * 512), 16, 0, 0);
      __builtin_amdgcn_global_load_lds(
        (const __attribute__((address_space(1))) u32*)(sP2 + so),
        (__attribute__((address_space(3))) u32*)(L + (16 + sl) * 512), 16, 0, 0);
      __builtin_amdgcn_global_load_lds(
        (const __attribute__((address_space(1))) u32*)(sP3 + so),
        (__attribute__((address_space(3))) u32*)(L + (24 + sl) * 512), 16, 0, 0);
    }
  };
  auto compute = [&](int buf){
    const u16* L = &Ls[buf][0] + lane * 8;
    #pragma unroll
    for (int h = 0; h < 2; ++h){
      const int sl = h * 4 + w;
      bf16x8 fa0 = *(const bf16x8*)(const void*)(L + (0  + sl) * 512);
      bf16x8 fa1 = *(const bf16x8*)(const void*)(L + (8  + sl) * 512);
      bf16x8 fb0 = *(const bf16x8*)(const void*)(L + (16 + sl) * 512);
      bf16x8 fb1 = *(const bf16x8*)(const void*)(L + (24 + sl) * 512);
      a00 = __builtin_amdgcn_mfma_f32_32x32x16_bf16(fa0, fb0, a00, 0, 0, 0);
      a01 = __builtin_amdgcn_mfma_f32_32x32x16_bf16(fa0, fb1, a01, 0, 0, 0);
      a10 = __builtin_amdgcn_mfma_f32_32x32x16_bf16(fa1, fb0, a10, 0, 0, 0);
      a11 = __builtin_amdgcn_mfma_f32_32x32x16_bf16(fa1, fb1, a11, 0, 0, 0);
    }
  };

  stage(0, 0);
  __syncthreads();
  for (int c = 0; c < 64; ++c){
    if (c < 63) stage((c + 1) & 1, c + 1);
    compute(c & 1);
    __syncthreads();
  }

  // ---- tree-reduce the 4 wave-partials (reuse Ls as f32 scratch) ----
  float* Rf = (float*)(&Ls[0][0]);       // 16384 floats
  f32x16 aq[4];
  aq[0] = a00; aq[1] = a01; aq[2] = a10; aq[3] = a11;
  if (w >= 2){
    float* o = Rf + (w - 2) * 4096 + lane;
    #pragma unroll
    for (int q = 0; q < 4; ++q)
      #pragma unroll
      for (int r = 0; r < 16; ++r)
        o[(q * 16 + r) * 64] = aq[q][r];
  }
  __syncthreads();
  if (w < 2){
    const float* o = Rf + w * 4096 + lane;
    #pragma unroll
    for (int q = 0; q < 4; ++q)
      #pragma unroll
      for (int r = 0; r < 16; ++r)
        aq[q][r] += o[(q * 16 + r) * 64];
  }
  __syncthreads();
  if (w == 1){
    float* o = Rf + lane;
    #pragma unroll
    for (int q = 0; q < 4; ++q)
      #pragma unroll
      for (int r = 0; r < 16; ++r)
        o[(q * 16 + r) * 64] = aq[q][r];
  }
  __syncthreads();
  if (w == 0){
    const float* o = Rf + lane;
    const int rhi = (lane >> 5) << 2;
    const int cl  = lane & 31;
    #pragma unroll
    for (int q = 0; q < 4; ++q){
      const int rbase = rowg * 64 + (q >> 1) * 32;
      const int cbase = colg * 64 + (q & 1) * 32;
      #pragma unroll
      for (int r = 0; r < 16; ++r){
        const int rl = (r & 3) + ((r >> 2) << 3) + rhi;
        const int row = rbase + rl;
        float v = aq[q][r] + o[(q * 16 + r) * 64];
        v *= ds[row];
        v = fmaxf(v, 0.f);
        Hout[(size_t)row * 256 + cbase + cl] = f2bf(v);
      }
    }
  }
}

// ---------------------------------------------------------------------------
// F=128 big GEMM (R8-proven register-direct pipeline).
// ---------------------------------------------------------------------------
template<int F, bool RELU, bool OUTF32>
__global__ __launch_bounds__(1024, 4) void gemm_pipe(
    const u16* __restrict__ Ab, const u16* __restrict__ Vt,
    const float* __restrict__ ds, u16* __restrict__ Hout, float* __restrict__ Fout){
  __shared__ float red[2][32][F];

  const int t = threadIdx.x, wave = t >> 6, lane = t & 63;
  const int ks = wave >> 2;
  const int cg = wave & 3;
  const int row0 = blockIdx.x * 32;
  const int colb = cg * (F / 4);

  const u16* pa = Ab + ((size_t)blockIdx.x * 512 + ks * 128) * 512 + lane * 8;

  f32x16 acc0;
  #pragma unroll
  for (int i = 0; i < 16; ++i) acc0[i] = 0.f;

  const u16* pb0 = Vt + ((size_t)cg * 512 + ks * 128) * 512 + lane * 8;
  bf16x8 aQ[4], b0Q[4];
  GLD(aQ[0],pa,"0");    GLD(b0Q[0],pb0,"0");
  GLD(aQ[1],pa,"1024"); GLD(b0Q[1],pb0,"1024");
  GLD(aQ[2],pa,"2048"); GLD(b0Q[2],pb0,"2048");
  GLD(aQ[3],pa,"3072"); GLD(b0Q[3],pb0,"3072");
  pa += 2048; pb0 += 2048;
  #define STEP1(U, OFF) \
    WAITV("6"); \
    acc0 = __builtin_amdgcn_mfma_f32_32x32x16_bf16(aQ[U], b0Q[U], acc0, 0, 0, 0); \
    GLD(aQ[U],pa,OFF); GLD(b0Q[U],pb0,OFF)
  for (int it = 0; it < 31; ++it){
    STEP1(0, "0");
    STEP1(1, "1024");
    STEP1(2, "2048");
    STEP1(3, "3072");
    pa += 2048; pb0 += 2048;
  }
  #undef STEP1
  WAITV("6");
  acc0 = __builtin_amdgcn_mfma_f32_32x32x16_bf16(aQ[0], b0Q[0], acc0, 0, 0, 0);
  WAITV("4");
  acc0 = __builtin_amdgcn_mfma_f32_32x32x16_bf16(aQ[1], b0Q[1], acc0, 0, 0, 0);
  WAITV("2");
  acc0 = __builtin_amdgcn_mfma_f32_32x32x16_bf16(aQ[2], b0Q[2], acc0, 0, 0, 0);
  WAITV("0");
  acc0 = __builtin_amdgcn_mfma_f32_32x32x16_bf16(aQ[3], b0Q[3], acc0, 0, 0, 0);

  const int rhi = (lane >> 5) << 2;
  const int cl  = lane & 31;
  if (ks >= 2){
    #pragma unroll
    for (int r = 0; r < 16; ++r)
      red[ks - 2][(r & 3) + ((r >> 2) << 3) + rhi][colb + cl] = acc0[r];
  }
  __syncthreads();
  if (ks < 2){
    #pragma unroll
    for (int r = 0; r < 16; ++r)
      acc0[r] += red[ks][(r & 3) + ((r >> 2) << 3) + rhi][colb + cl];
  }
  __syncthreads();
  if (ks == 1){
    #pragma unroll
    for (int r = 0; r < 16; ++r)
      red[0][(r & 3) + ((r >> 2) << 3) + rhi][colb + cl] = acc0[r];
  }
  __syncthreads();
  if (ks == 0){
    #pragma unroll
    for (int r = 0; r < 16; ++r){
      const int rl = (r & 3) + ((r >> 2) << 3) + rhi;
      float v = acc0[r] + red[0][rl][colb + cl];
      const int row = row0 + rl;
      v *= ds[row];
      if (RELU) v = fmaxf(v, 0.f);
      if (OUTF32) Fout[(size_t)row * F + colb + cl] = v;
      else        Hout[(size_t)row * F + colb + cl] = f2bf(v);
    }
  }
}

// ---------------------------------------------------------------------------
// Attention scores: sc[i] = tanh(Z[i,:] @ Wl^T + bl) @ q + b
// ---------------------------------------------------------------------------
__device__ __forceinline__ float tanh_fast(float x){
  x = fminf(fmaxf(x, -15.f), 15.f);
  float e = __expf(2.f * x);
  return (e - 1.f) / (e + 1.f);
}

__global__ __launch_bounds__(256) void attn_scores(
    const float* __restrict__ Z, const float* __restrict__ Wl,
    const float* __restrict__ bl, const float* __restrict__ q,
    const float* __restrict__ bsc, float* __restrict__ sc){
  __shared__ float wl[128 * 128];          // 64 KiB exactly, swizzled
  const int t = threadIdx.x, lane = t & 63, wave = t >> 6;
  for (int j = 0; j < 64; ++j){
    int idx = j * 256 + t;
    int o = idx >> 7, k = idx & 127;
    int c = k >> 2, e = k & 3;
    wl[o * 128 + (((c ^ (o & 31)) << 2) | e)] = Wl[idx];
  }
  __syncthreads();
  const float bl0 = bl[lane], bl1 = bl[lane + 64];
  const float q0  = q[lane],  q1  = q[lane + 64];
  const float bb  = bsc[0];
  const int r0 = blockIdx.x * 16;
  for (int rr = 0; rr < 4; ++rr){
    int r = r0 + wave * 4 + rr;
    float d0 = 0.f, d1 = 0.f;
    #pragma unroll
    for (int c = 0; c < 32; ++c){
      float4 zv = *(const float4*)(Z + (size_t)r * 128 + c * 4);
      float4 w0 = *(const float4*)&wl[ lane      * 128 + ((c ^ (lane & 31)) << 2)];
      float4 w1 = *(const float4*)&wl[(lane + 64)* 128 + ((c ^ (lane & 31)) << 2)];
      d0 += zv.x*w0.x + zv.y*w0.y + zv.z*w0.z + zv.w*w0.w;
      d1 += zv.x*w1.x + zv.y*w1.y + zv.z*w1.z + zv.w*w1.w;
    }
    float s = tanh_fast(d0 + bl0) * q0 + tanh_fast(d1 + bl1) * q1;
    #pragma unroll
    for (int off = 32; off > 0; off >>= 1) s += __shfl_down(s, off, 64);
    if (lane == 0) sc[r] = s + bb;
  }
}

__global__ __launch_bounds__(1024) void softmax_red(
    const float* __restrict__ sc, float* __restrict__ sred){
  const int t = threadIdx.x, lane = t & 63, wave = t >> 6;
  __shared__ float red[16];
  float m = -1e30f;
  for (int i = t; i < 8192; i += 1024) m = fmaxf(m, sc[i]);
  #pragma unroll
  for (int off = 32; off > 0; off >>= 1) m = fmaxf(m, __shfl_down(m, off, 64));
  if (lane == 0) red[wave] = m;
  __syncthreads();
  if (t == 0){
    float mm = red[0];
    for (int w = 1; w < 16; ++w) mm = fmaxf(mm, red[w]);
    red[0] = mm;
  }
  __syncthreads();
  const float bmax = red[0];
  __syncthreads();
  float s = 0.f;
  for (int i = t; i < 8192; i += 1024) s += __expf(sc[i] - bmax);
  #pragma unroll
  for (int off = 32; off > 0; off >>= 1) s += __shfl_down(s, off, 64);
  if (lane == 0) red[wave] = s;
  __syncthreads();
  if (t == 0){
    float ss = 0.f;
    for (int w = 0; w < 16; ++w) ss += red[w];
    sred[0] = bmax; sred[1] = ss;
  }
}

__global__ __launch_bounds__(256) void weighted_part(
    const float* __restrict__ sc, const float* __restrict__ sred,
    const float* __restrict__ Z, float* __restrict__ part){
  const int blk = blockIdx.x, t = threadIdx.x;
  const int o = t & 127, h = t >> 7;
  const float bmax = sred[0], inv = 1.f / sred[1];
  float acc = 0.f;
  const int i0 = blk * 128;
  for (int i = i0 + h; i < i0 + 128; i += 2){
    float w = __expf(sc[i] - bmax) * inv;
    acc += w * Z[(size_t)i * 128 + o];
  }
  __shared__ float l[256];
  l[t] = acc;
  __syncthreads();
  if (h == 0) part[blk * 128 + o] = l[o] + l[o + 128];
}

__global__ __launch_bounds__(128) void final_red(
    const float* __restrict__ part, float* __restrict__ out){
  const int o = threadIdx.x;
  float s = 0.f;
  for (int b = 0; b < 64; ++b) s += part[b * 128 + o];
  out[o] = s;
}

// ---------------------------------------------------------------------------
extern "C" void kernel_launch(void* const* d_in, const int* in_sizes, int n_in,
                              void* d_out, int out_size, void* d_ws, size_t ws_size,
                              hipStream_t stream){
  const float* x  = (const float*)d_in[0];
  const float* A  = (const float*)d_in[1];
  const float* W1 = (const float*)d_in[2];
  const float* W2 = (const float*)d_in[3];
  const float* W3 = (const float*)d_in[4];
  const float* Wl = (const float*)d_in[5];
  const float* bl = (const float*)d_in[6];
  const float* q  = (const float*)d_in[7];
  const float* b  = (const float*)d_in[8];
  float* out = (float*)d_out;
  char* ws = (char*)d_ws;

  u16*   AB   = (u16*)(ws);                      // 128 MiB, tiled
  float* DS   = (float*)(ws + 134217728);        // 32 KiB
  u16*   VT   = (u16*)(ws + 134250496);          // 4 MiB, tiled
  u16*   HB   = (u16*)(ws + 138444800);          // 4 MiB [8192][256] row-major
  float* SC   = (float*)(ws + 142639104);        // 8192 f32 scores
  float* SP   = (float*)(ws + 142671872);        // 64*128 f32
  float* SRED = (float*)(ws + 142704640);        // {max, sumexp}

  rowsum_tileA<<<256, 1024, 0, stream>>>(A, AB, DS);
  // layer 1
  small_gemm<128, 256, false><<<512, 256, 0, stream>>>(x, W1, DS, VT);
  gemm_rt<<<512, 256, 0, stream>>>(AB, VT, DS, HB);
  // layer 2
  small_gemm<256, 256, true><<<512, 256, 0, stream>>>(HB, W2, DS, VT);
  gemm_rt<<<512, 256, 0, stream>>>(AB, VT, DS, HB);
  // --- R15 instrumentation: 3 extra idempotent replays of gemm_rt.
  // T_gemm256 = (total_R15 - 380.9)/3. Remove in R16.
  gemm_rt<<<512, 256, 0, stream>>>(AB, VT, DS, HB);
  gemm_rt<<<512, 256, 0, stream>>>(AB, VT, DS, HB);
  gemm_rt<<<512, 256, 0, stream>>>(AB, VT, DS, HB);
  // layer 3 -> z_context f32 straight into d_out
  small_gemm<256, 128, true><<<256, 256, 0, stream>>>(HB, W3, DS, VT);
  gemm_pipe<128, false, true><<<256, 1024, 0, stream>>>(AB, VT, DS, nullptr, out);
  // attention pooling
  attn_scores<<<512, 256, 0, stream>>>(out, Wl, bl, q, b, SC);
  softmax_red<<<1, 1024, 0, stream>>>(SC, SRED);
  weighted_part<<<64, 256, 0, stream>>>(SC, SRED, out, SP);
  final_red<<<1, 128, 0, stream>>>(SP, out + 8192 * 128);
}

// Round 16
// 384.628 us; speedup vs baseline: 1.3644x; 1.3644x over previous
//
#include <hip/hip_runtime.h>

typedef unsigned short u16;
typedef unsigned int   u32;
typedef __bf16 bf16x8 __attribute__((ext_vector_type(8)));
typedef float  f32x16 __attribute__((ext_vector_type(16)));

__device__ __forceinline__ u16 f2bf(float f){
  u32 u = __float_as_uint(f);
  u32 r = (u + 0x7FFFu + ((u >> 16) & 1u)) >> 16;   // RNE
  return (u16)r;
}

// ===========================================================================
// TILED OPERAND LAYOUT (validated R8): tile = 32 rows x 16 k = 1KB,
// lane-ordered; consumer ds_read_b128/gload_lds are linear + conflict-free.
//
// R15 measurement: gemm_rt(F=256) = 48.0us (line-rate floor 27us) -> the
// F=256 pair is only 96us of 381. R16 attacks the rest:
//  - gemm_pipe128 had 4x A-duplication (4 col-group waves re-read the same
//    A privately) at 1 block/CU -> replaced by gemm_rt128 (32x64 tiles,
//    grid 512, LDS-staged, no dup, 2 blocks/CU).
//  - rowsum's LDS-transpose write was ~16-way bank-conflicted (bank =
//    4r + 2(q&1), wave-constant) -> XOR tl with (tile&7) (tile = q>>2
//    spans bits 0-2) -> 2-way (free). Copy-out applies the same XOR.
// ===========================================================================

// ---------------------------------------------------------------------------
// Pass 1: row sums + f32->bf16 + transpose to tiled layout via LDS.
// ---------------------------------------------------------------------------
__global__ __launch_bounds__(1024) void rowsum_tileA(
    const float* __restrict__ A, u16* __restrict__ Ab, float* __restrict__ ds){
  __shared__ u16 lt[8192];               // 16 tiles x 512 u16 = 16 KB
  const int t = threadIdx.x;
  const int r = t >> 5, q = t & 31;      // row 0..31, 32 threads/row
  const int rg = blockIdx.x;
  const float* ar = A + ((size_t)rg * 32 + r) * 8192;
  float s = 0.f;
  for (int ch = 0; ch < 32; ++ch){
    #pragma unroll
    for (int j = 0; j < 2; ++j){
      const int c4 = ch * 64 + j * 32 + q;           // float4 col index
      float4 v = ((const float4*)ar)[c4];
      s += (v.x + v.y) + (v.z + v.w);
      const int cl = (j * 32 + q) * 4;               // local col 0..255
      const int tile = cl >> 4;
      const int tl   = (r | (((cl >> 3) & 1) << 5)) ^ (tile & 7);  // swizzled
      const int idx  = tile * 512 + tl * 8 + (cl & 7);
      ushort4 o;
      o.x = f2bf(v.x); o.y = f2bf(v.y); o.z = f2bf(v.z); o.w = f2bf(v.w);
      *(ushort4*)(lt + idx) = o;
    }
    __syncthreads();
    {
      const int tile = t >> 6, tl = t & 63;          // un-swizzle on read
      uint4 v = *(const uint4*)(lt + tile * 512 + (tl ^ (tile & 7)) * 8);
      uint4* dst = (uint4*)(Ab + ((size_t)rg * 512 + ch * 16) * 512);
      dst[t] = v;
    }
    __syncthreads();
  }
  #pragma unroll
  for (int m = 16; m > 0; m >>= 1) s += __shfl_xor(s, m, 64);
  if (q == 0) ds[rg * 32 + r] = rsqrtf(s);
}

// ---------------------------------------------------------------------------
// Small feature GEMM: Vt tiles = bf16( ds[i] * sum_k in[i][k] * W[k][o] )
// ---------------------------------------------------------------------------
template<int K, int F, bool INBF16>
__global__ __launch_bounds__(256) void small_gemm(
    const void* __restrict__ inp, const float* __restrict__ W,
    const float* __restrict__ ds, u16* __restrict__ Vt){
  constexpr int G   = 256 / F;     // 1 (F=256) or 2 (F=128)
  constexpr int RPB = 16 * G;      // rows per block
  __shared__ float xs[RPB * K];
  const int t  = threadIdx.x;
  const int r0 = blockIdx.x * RPB;
  if constexpr (INBF16){
    const u16* ip = (const u16*)inp + (size_t)r0 * K;
    constexpr int IT = (RPB * K) / (256 * 8);
    #pragma unroll
    for (int j = 0; j < IT; ++j){
      int c = j * 256 + t;
      uint4 v = ((const uint4*)ip)[c];
      float* xp = xs + c * 8;
      xp[0] = __uint_as_float((v.x & 0xFFFFu) << 16);
      xp[1] = __uint_as_float(v.x & 0xFFFF0000u);
      xp[2] = __uint_as_float((v.y & 0xFFFFu) << 16);
      xp[3] = __uint_as_float(v.y & 0xFFFF0000u);
      xp[4] = __uint_as_float((v.z & 0xFFFFu) << 16);
      xp[5] = __uint_as_float(v.z & 0xFFFF0000u);
      xp[6] = __uint_as_float((v.w & 0xFFFFu) << 16);
      xp[7] = __uint_as_float(v.w & 0xFFFF0000u);
    }
  } else {
    const float* ip = (const float*)inp + (size_t)r0 * K;
    constexpr int IT = (RPB * K) / (256 * 4);
    #pragma unroll
    for (int j = 0; j < IT; ++j){
      int c = j * 256 + t;
      ((float4*)xs)[c] = ((const float4*)ip)[c];
    }
  }
  __syncthreads();
  const int o = t % F, g = t / F;
  float acc[16];
  #pragma unroll
  for (int r = 0; r < 16; ++r) acc[r] = 0.f;
  const float* xr = xs + g * 16 * K;
  for (int k = 0; k < K; k += 4){
    float w0 = W[(k+0)*F + o];
    float w1 = W[(k+1)*F + o];
    float w2 = W[(k+2)*F + o];
    float w3 = W[(k+3)*F + o];
    #pragma unroll
    for (int r = 0; r < 16; ++r){
      float4 xv = *(const float4*)(xr + r*K + k);
      acc[r] += xv.x*w0 + xv.y*w1 + xv.z*w2 + xv.w*w3;
    }
  }
  const int rb = r0 + g * 16;              // 16-aligned -> one k-tile
  union { u16 u[16]; uint4 v[2]; } pk;
  #pragma unroll
  for (int r = 0; r < 16; ++r) pk.u[r] = f2bf(acc[r] * ds[rb + r]);
  const size_t tile = ((size_t)(o >> 5) * 512 + (rb >> 4)) * 512;
  uint4* dst = (uint4*)(Vt + tile + (size_t)(o & 31) * 8);
  dst[0]  = pk.v[0];
  dst[32] = pk.v[1];
}

// ---------------------------------------------------------------------------
// F=256 big GEMM, register-tiled wave-K-split LDS (R14, measured 48us).
// ---------------------------------------------------------------------------
__global__ __launch_bounds__(256) void gemm_rt(
    const u16* __restrict__ Ab, const u16* __restrict__ Vt,
    const float* __restrict__ ds, u16* __restrict__ Hout){
  __shared__ u16 Ls[2][32 * 512];        // 2 x 32KB
  const int t = threadIdx.x, w = t >> 6, lane = t & 63;
  const int rowg = blockIdx.x & 127;
  const int colg = blockIdx.x >> 7;      // 0..3

  const u16* sP0 = Ab + ((size_t)(rowg * 2 + 0) * 512) * 512 + lane * 8;
  const u16* sP1 = Ab + ((size_t)(rowg * 2 + 1) * 512) * 512 + lane * 8;
  const u16* sP2 = Vt + ((size_t)(colg * 2 + 0) * 512) * 512 + lane * 8;
  const u16* sP3 = Vt + ((size_t)(colg * 2 + 1) * 512) * 512 + lane * 8;

  f32x16 a00, a01, a10, a11;
  #pragma unroll
  for (int i = 0; i < 16; ++i){ a00[i]=0.f; a01[i]=0.f; a10[i]=0.f; a11[i]=0.f; }

  auto stage = [&](int buf, int c){
    u16* L = &Ls[buf][0] + lane * 8;
    #pragma unroll
    for (int h = 0; h < 2; ++h){
      const int kt = c * 8 + h * 4 + w;         // global k-tile
      const int sl = h * 4 + w;                 // local slot 0..7
      const size_t so = (size_t)kt * 512;
      __builtin_amdgcn_global_load_lds(
        (const __attribute__((address_space(1))) u32*)(sP0 + so),
        (__attribute__((address_space(3))) u32*)(L + (0  + sl) * 512), 16, 0, 0);
      __builtin_amdgcn_global_load_lds(
        (const __attribute__((address_space(1))) u32*)(sP1 + so),
        (__attribute__((address_space(3))) u32*)(L + (8  + sl) * 512), 16, 0, 0);
      __builtin_amdgcn_global_load_lds(
        (const __attribute__((address_space(1))) u32*)(sP2 + so),
        (__attribute__((address_space(3))) u32*)(L + (16 + sl) * 512), 16, 0, 0);
      __builtin_amdgcn_global_load_lds(
        (const __attribute__((address_space(1))) u32*)(sP3 + so),
        (__attribute__((address_space(3))) u32*)(L + (24 + sl) * 512), 16, 0, 0);
    }
  };
  auto compute = [&](int buf){
    const u16* L = &Ls[buf][0] + lane * 8;
    #pragma unroll
    for (int h = 0; h < 2; ++h){
      const int sl = h * 4 + w;
      bf16x8 fa0 = *(const bf16x8*)(const void*)(L + (0  + sl) * 512);
      bf16x8 fa1 = *(const bf16x8*)(const void*)(L + (8  + sl) * 512);
      bf16x8 fb0 = *(const bf16x8*)(const void*)(L + (16 + sl) * 512);
      bf16x8 fb1 = *(const bf16x8*)(const void*)(L + (24 + sl) * 512);
      a00 = __builtin_amdgcn_mfma_f32_32x32x16_bf16(fa0, fb0, a00, 0, 0, 0);
      a01 = __builtin_amdgcn_mfma_f32_32x32x16_bf16(fa0, fb1, a01, 0, 0, 0);
      a10 = __builtin_amdgcn_mfma_f32_32x32x16_bf16(fa1, fb0, a10, 0, 0, 0);
      a11 = __builtin_amdgcn_mfma_f32_32x32x16_bf16(fa1, fb1, a11, 0, 0, 0);
    }
  };

  stage(0, 0);
  __syncthreads();
  for (int c = 0; c < 64; ++c){
    if (c < 63) stage((c + 1) & 1, c + 1);
    compute(c & 1);
    __syncthreads();
  }

  // ---- tree-reduce the 4 wave-partials (reuse Ls as f32 scratch) ----
  float* Rf = (float*)(&Ls[0][0]);       // 16384 floats
  f32x16 aq[4];
  aq[0] = a00; aq[1] = a01; aq[2] = a10; aq[3] = a11;
  if (w >= 2){
    float* o = Rf + (w - 2) * 4096 + lane;
    #pragma unroll
    for (int q = 0; q < 4; ++q)
      #pragma unroll
      for (int r = 0; r < 16; ++r)
        o[(q * 16 + r) * 64] = aq[q][r];
  }
  __syncthreads();
  if (w < 2){
    const float* o = Rf + w * 4096 + lane;
    #pragma unroll
    for (int q = 0; q < 4; ++q)
      #pragma unroll
      for (int r = 0; r < 16; ++r)
        aq[q][r] += o[(q * 16 + r) * 64];
  }
  __syncthreads();
  if (w == 1){
    float* o = Rf + lane;
    #pragma unroll
    for (int q = 0; q < 4; ++q)
      #pragma unroll
      for (int r = 0; r < 16; ++r)
        o[(q * 16 + r) * 64] = aq[q][r];
  }
  __syncthreads();
  if (w == 0){
    const float* o = Rf + lane;
    const int rhi = (lane >> 5) << 2;
    const int cl  = lane & 31;
    #pragma unroll
    for (int q = 0; q < 4; ++q){
      const int rbase = rowg * 64 + (q >> 1) * 32;
      const int cbase = colg * 64 + (q & 1) * 32;
      #pragma unroll
      for (int r = 0; r < 16; ++r){
        const int rl = (r & 3) + ((r >> 2) << 3) + rhi;
        const int row = rbase + rl;
        float v = aq[q][r] + o[(q * 16 + r) * 64];
        v *= ds[row];
        v = fmaxf(v, 0.f);
        Hout[(size_t)row * 256 + cbase + cl] = f2bf(v);
      }
    }
  }
}

// ---------------------------------------------------------------------------
// F=128 big GEMM, gemm_rt structure at 32x64 tiles (R16 — replaces the
// 4x-A-duplicating gemm_pipe). Grid 512 = 256 rowg (fast) x 2 colg;
// 2 blocks/CU; 3 panels (A, B0, B1), BK=128, LDS 48 KB; f32 out, no relu.
// ---------------------------------------------------------------------------
__global__ __launch_bounds__(256) void gemm_rt128(
    const u16* __restrict__ Ab, const u16* __restrict__ Vt,
    const float* __restrict__ ds, float* __restrict__ Fout){
  __shared__ u16 Ls[2][24 * 512];        // 2 x 24KB
  const int t = threadIdx.x, w = t >> 6, lane = t & 63;
  const int rowg = blockIdx.x & 255;
  const int colg = blockIdx.x >> 8;      // 0..1

  const u16* sA  = Ab + ((size_t)rowg * 512) * 512 + lane * 8;
  const u16* sB0 = Vt + ((size_t)(colg * 2 + 0) * 512) * 512 + lane * 8;
  const u16* sB1 = Vt + ((size_t)(colg * 2 + 1) * 512) * 512 + lane * 8;

  f32x16 p0, p1;
  #pragma unroll
  for (int i = 0; i < 16; ++i){ p0[i] = 0.f; p1[i] = 0.f; }

  auto stage = [&](int buf, int c){
    u16* L = &Ls[buf][0] + lane * 8;
    #pragma unroll
    for (int h = 0; h < 2; ++h){
      const int kt = c * 8 + h * 4 + w;
      const int sl = h * 4 + w;
      const size_t so = (size_t)kt * 512;
      __builtin_amdgcn_global_load_lds(
        (const __attribute__((address_space(1))) u32*)(sA + so),
        (__attribute__((address_space(3))) u32*)(L + (0  + sl) * 512), 16, 0, 0);
      __builtin_amdgcn_global_load_lds(
        (const __attribute__((address_space(1))) u32*)(sB0 + so),
        (__attribute__((address_space(3))) u32*)(L + (8  + sl) * 512), 16, 0, 0);
      __builtin_amdgcn_global_load_lds(
        (const __attribute__((address_space(1))) u32*)(sB1 + so),
        (__attribute__((address_space(3))) u32*)(L + (16 + sl) * 512), 16, 0, 0);
    }
  };
  auto compute = [&](int buf){
    const u16* L = &Ls[buf][0] + lane * 8;
    #pragma unroll
    for (int h = 0; h < 2; ++h){
      const int sl = h * 4 + w;
      bf16x8 fa  = *(const bf16x8*)(const void*)(L + (0  + sl) * 512);
      bf16x8 fb0 = *(const bf16x8*)(const void*)(L + (8  + sl) * 512);
      bf16x8 fb1 = *(const bf16x8*)(const void*)(L + (16 + sl) * 512);
      p0 = __builtin_amdgcn_mfma_f32_32x32x16_bf16(fa, fb0, p0, 0, 0, 0);
      p1 = __builtin_amdgcn_mfma_f32_32x32x16_bf16(fa, fb1, p1, 0, 0, 0);
    }
  };

  stage(0, 0);
  __syncthreads();
  for (int c = 0; c < 64; ++c){
    if (c < 63) stage((c + 1) & 1, c + 1);
    compute(c & 1);
    __syncthreads();
  }

  // ---- tree-reduce the 4 wave-partials (32x64 each; reuse Ls) ----
  float* Rf = (float*)(&Ls[0][0]);       // need 2 x 2048 f32 = 16 KB
  f32x16 aq[2];
  aq[0] = p0; aq[1] = p1;
  if (w >= 2){
    float* o = Rf + (w - 2) * 2048 + lane;
    #pragma unroll
    for (int q = 0; q < 2; ++q)
      #pragma unroll
      for (int r = 0; r < 16; ++r)
        o[(q * 16 + r) * 64] = aq[q][r];
  }
  __syncthreads();
  if (w < 2){
    const float* o = Rf + w * 2048 + lane;
    #pragma unroll
    for (int q = 0; q < 2; ++q)
      #pragma unroll
      for (int r = 0; r < 16; ++r)
        aq[q][r] += o[(q * 16 + r) * 64];
  }
  __syncthreads();
  if (w == 1){
    float* o = Rf + lane;
    #pragma unroll
    for (int q = 0; q < 2; ++q)
      #pragma unroll
      for (int r = 0; r < 16; ++r)
        o[(q * 16 + r) * 64] = aq[q][r];
  }
  __syncthreads();
  if (w == 0){
    const float* o = Rf + lane;
    const int rhi = (lane >> 5) << 2;
    const int cl  = lane & 31;
    #pragma unroll
    for (int q = 0; q < 2; ++q){
      const int cbase = colg * 64 + q * 32;
      #pragma unroll
      for (int r = 0; r < 16; ++r){
        const int rl = (r & 3) + ((r >> 2) << 3) + rhi;
        const int row = rowg * 32 + rl;
        float v = aq[q][r] + o[(q * 16 + r) * 64];
        Fout[(size_t)row * 128 + cbase + cl] = v * ds[row];
      }
    }
  }
}

// ---------------------------------------------------------------------------
// Attention scores: sc[i] = tanh(Z[i,:] @ Wl^T + bl) @ q + b
// ---------------------------------------------------------------------------
__device__ __forceinline__ float tanh_fast(float x){
  x = fminf(fmaxf(x, -15.f), 15.f);
  float e = __expf(2.f * x);
  return (e - 1.f) / (e + 1.f);
}

__global__ __launch_bounds__(256) void attn_scores(
    const float* __restrict__ Z, const float* __restrict__ Wl,
    const float* __restrict__ bl, const float* __restrict__ q,
    const float* __restrict__ bsc, float* __restrict__ sc){
  __shared__ float wl[128 * 128];          // 64 KiB exactly, swizzled
  const int t = threadIdx.x, lane = t & 63, wave = t >> 6;
  for (int j = 0; j < 64; ++j){
    int idx = j * 256 + t;
    int o = idx >> 7, k = idx & 127;
    int c = k >> 2, e = k & 3;
    wl[o * 128 + (((c ^ (o & 31)) << 2) | e)] = Wl[idx];
  }
  __syncthreads();
  const float bl0 = bl[lane], bl1 = bl[lane + 64];
  const float q0  = q[lane],  q1  = q[lane + 64];
  const float bb  = bsc[0];
  const int r0 = blockIdx.x * 16;
  for (int rr = 0; rr < 4; ++rr){
    int r = r0 + wave * 4 + rr;
    float d0 = 0.f, d1 = 0.f;
    #pragma unroll
    for (int c = 0; c < 32; ++c){
      float4 zv = *(const float4*)(Z + (size_t)r * 128 + c * 4);
      float4 w0 = *(const float4*)&wl[ lane      * 128 + ((c ^ (lane & 31)) << 2)];
      float4 w1 = *(const float4*)&wl[(lane + 64)* 128 + ((c ^ (lane & 31)) << 2)];
      d0 += zv.x*w0.x + zv.y*w0.y + zv.z*w0.z + zv.w*w0.w;
      d1 += zv.x*w1.x + zv.y*w1.y + zv.z*w1.z + zv.w*w1.w;
    }
    float s = tanh_fast(d0 + bl0) * q0 + tanh_fast(d1 + bl1) * q1;
    #pragma unroll
    for (int off = 32; off > 0; off >>= 1) s += __shfl_down(s, off, 64);
    if (lane == 0) sc[r] = s + bb;
  }
}

__global__ __launch_bounds__(1024) void softmax_red(
    const float* __restrict__ sc, float* __restrict__ sred){
  const int t = threadIdx.x, lane = t & 63, wave = t >> 6;
  __shared__ float red[16];
  float m = -1e30f;
  for (int i = t; i < 8192; i += 1024) m = fmaxf(m, sc[i]);
  #pragma unroll
  for (int off = 32; off > 0; off >>= 1) m = fmaxf(m, __shfl_down(m, off, 64));
  if (lane == 0) red[wave] = m;
  __syncthreads();
  if (t == 0){
    float mm = red[0];
    for (int w = 1; w < 16; ++w) mm = fmaxf(mm, red[w]);
    red[0] = mm;
  }
  __syncthreads();
  const float bmax = red[0];
  __syncthreads();
  float s = 0.f;
  for (int i = t; i < 8192; i += 1024) s += __expf(sc[i] - bmax);
  #pragma unroll
  for (int off = 32; off > 0; off >>= 1) s += __shfl_down(s, off, 64);
  if (lane == 0) red[wave] = s;
  __syncthreads();
  if (t == 0){
    float ss = 0.f;
    for (int w = 0; w < 16; ++w) ss += red[w];
    sred[0] = bmax; sred[1] = ss;
  }
}

__global__ __launch_bounds__(256) void weighted_part(
    const float* __restrict__ sc, const float* __restrict__ sred,
    const float* __restrict__ Z, float* __restrict__ part){
  const int blk = blockIdx.x, t = threadIdx.x;
  const int o = t & 127, h = t >> 7;
  const float bmax = sred[0], inv = 1.f / sred[1];
  float acc = 0.f;
  const int i0 = blk * 128;
  for (int i = i0 + h; i < i0 + 128; i += 2){
    float w = __expf(sc[i] - bmax) * inv;
    acc += w * Z[(size_t)i * 128 + o];
  }
  __shared__ float l[256];
  l[t] = acc;
  __syncthreads();
  if (h == 0) part[blk * 128 + o] = l[o] + l[o + 128];
}

__global__ __launch_bounds__(128) void final_red(
    const float* __restrict__ part, float* __restrict__ out){
  const int o = threadIdx.x;
  float s = 0.f;
  for (int b = 0; b < 64; ++b) s += part[b * 128 + o];
  out[o] = s;
}

// ---------------------------------------------------------------------------
extern "C" void kernel_launch(void* const* d_in, const int* in_sizes, int n_in,
                              void* d_out, int out_size, void* d_ws, size_t ws_size,
                              hipStream_t stream){
  const float* x  = (const float*)d_in[0];
  const float* A  = (const float*)d_in[1];
  const float* W1 = (const float*)d_in[2];
  const float* W2 = (const float*)d_in[3];
  const float* W3 = (const float*)d_in[4];
  const float* Wl = (const float*)d_in[5];
  const float* bl = (const float*)d_in[6];
  const float* q  = (const float*)d_in[7];
  const float* b  = (const float*)d_in[8];
  float* out = (float*)d_out;
  char* ws = (char*)d_ws;

  u16*   AB   = (u16*)(ws);                      // 128 MiB, tiled
  float* DS   = (float*)(ws + 134217728);        // 32 KiB
  u16*   VT   = (u16*)(ws + 134250496);          // 4 MiB, tiled
  u16*   HB   = (u16*)(ws + 138444800);          // 4 MiB [8192][256] row-major
  float* SC   = (float*)(ws + 142639104);        // 8192 f32 scores
  float* SP   = (float*)(ws + 142671872);        // 64*128 f32
  float* SRED = (float*)(ws + 142704640);        // {max, sumexp}

  rowsum_tileA<<<256, 1024, 0, stream>>>(A, AB, DS);
  // layer 1
  small_gemm<128, 256, false><<<512, 256, 0, stream>>>(x, W1, DS, VT);
  gemm_rt<<<512, 256, 0, stream>>>(AB, VT, DS, HB);
  // layer 2
  small_gemm<256, 256, true><<<512, 256, 0, stream>>>(HB, W2, DS, VT);
  gemm_rt<<<512, 256, 0, stream>>>(AB, VT, DS, HB);
  // layer 3 -> z_context f32 straight into d_out
  small_gemm<256, 128, true><<<256, 256, 0, stream>>>(HB, W3, DS, VT);
  gemm_rt128<<<512, 256, 0, stream>>>(AB, VT, DS, out);
  // attention pooling
  attn_scores<<<512, 256, 0, stream>>>(out, Wl, bl, q, b, SC);
  softmax_red<<<1, 1024, 0, stream>>>(SC, SRED);
  weighted_part<<<64, 256, 0, stream>>>(SC, SRED, out, SP);
  final_red<<<1, 128, 0, stream>>>(SP, out + 8192 * 128);
}

// Round 17
// 307.878 us; speedup vs baseline: 1.7045x; 1.2493x over previous
//
#include <hip/hip_runtime.h>

typedef unsigned short u16;
typedef unsigned int   u32;
typedef __bf16 bf16x8 __attribute__((ext_vector_type(8)));
typedef float  f32x16 __attribute__((ext_vector_type(16)));

__device__ __forceinline__ u16 f2bf(float f){
  u32 u = __float_as_uint(f);
  u32 r = (u + 0x7FFFu + ((u >> 16) & 1u)) >> 16;   // RNE
  return (u16)r;
}

// ===========================================================================
// TILED OPERAND LAYOUT (validated R8): tile = 32 rows x 16 k = 1KB,
// elem (row,k) -> tile (row>>5, k>>4), lane = (row&31)|(((k>>3)&1)<<5),
// byte = tile*1024 + lane*16 + (k&7)*2. Contiguous, lane-ordered.
//
// R16 post-mortem: whole-kernel swaps moved the total <2% -> attribution was
// wrong. Re-audit found small_gemm's 256x LDS redundancy (every thread reads
// all 16 rows privately): 2.1GB LDS reads for layer 2 (~30us), ~60us total
// across the three smalls — scalar-FMA matmuls (G10 violation).
// R17: small gemms for layers 2,3 -> MFMA on tiled operands, register-direct
// (zero LDS, zero barriers); gemm_rt now emits H in tiled layout; prep_w
// pre-tiles W2/W3 as bf16 fragments.
// ===========================================================================

// ---------------------------------------------------------------------------
// Pass 1: row sums + f32->bf16 + transpose to tiled layout via LDS (R16 swz).
// ---------------------------------------------------------------------------
__global__ __launch_bounds__(1024) void rowsum_tileA(
    const float* __restrict__ A, u16* __restrict__ Ab, float* __restrict__ ds){
  __shared__ u16 lt[8192];               // 16 tiles x 512 u16 = 16 KB
  const int t = threadIdx.x;
  const int r = t >> 5, q = t & 31;      // row 0..31, 32 threads/row
  const int rg = blockIdx.x;
  const float* ar = A + ((size_t)rg * 32 + r) * 8192;
  float s = 0.f;
  for (int ch = 0; ch < 32; ++ch){
    #pragma unroll
    for (int j = 0; j < 2; ++j){
      const int c4 = ch * 64 + j * 32 + q;           // float4 col index
      float4 v = ((const float4*)ar)[c4];
      s += (v.x + v.y) + (v.z + v.w);
      const int cl = (j * 32 + q) * 4;               // local col 0..255
      const int tile = cl >> 4;
      const int tl   = (r | (((cl >> 3) & 1) << 5)) ^ (tile & 7);  // swizzled
      const int idx  = tile * 512 + tl * 8 + (cl & 7);
      ushort4 o;
      o.x = f2bf(v.x); o.y = f2bf(v.y); o.z = f2bf(v.z); o.w = f2bf(v.w);
      *(ushort4*)(lt + idx) = o;
    }
    __syncthreads();
    {
      const int tile = t >> 6, tl = t & 63;          // un-swizzle on read
      uint4 v = *(const uint4*)(lt + tile * 512 + (tl ^ (tile & 7)) * 8);
      uint4* dst = (uint4*)(Ab + ((size_t)rg * 512 + ch * 16) * 512);
      dst[t] = v;
    }
    __syncthreads();
  }
  #pragma unroll
  for (int m = 16; m > 0; m >>= 1) s += __shfl_xor(s, m, 64);
  if (q == 0) ds[rg * 32 + r] = rsqrtf(s);
}

// ---------------------------------------------------------------------------
// Layer-1 small GEMM (reads f32 x; kept from R8): Vt = (ds * x@W1)^T tiled.
// ---------------------------------------------------------------------------
template<int K, int F>
__global__ __launch_bounds__(256) void small_gemm(
    const float* __restrict__ inp, const float* __restrict__ W,
    const float* __restrict__ ds, u16* __restrict__ Vt){
  constexpr int RPB = 16;
  __shared__ float xs[RPB * K];
  const int t  = threadIdx.x;
  const int r0 = blockIdx.x * RPB;
  const float* ip = inp + (size_t)r0 * K;
  constexpr int IT = (RPB * K) / (256 * 4);
  #pragma unroll
  for (int j = 0; j < IT; ++j){
    int c = j * 256 + t;
    ((float4*)xs)[c] = ((const float4*)ip)[c];
  }
  __syncthreads();
  const int o = t % F;
  float acc[16];
  #pragma unroll
  for (int r = 0; r < 16; ++r) acc[r] = 0.f;
  for (int k = 0; k < K; k += 4){
    float w0 = W[(k+0)*F + o];
    float w1 = W[(k+1)*F + o];
    float w2 = W[(k+2)*F + o];
    float w3 = W[(k+3)*F + o];
    #pragma unroll
    for (int r = 0; r < 16; ++r){
      float4 xv = *(const float4*)(xs + r*K + k);
      acc[r] += xv.x*w0 + xv.y*w1 + xv.z*w2 + xv.w*w3;
    }
  }
  const int rb = r0;                       // 16-aligned -> one k-tile
  union { u16 u[16]; uint4 v[2]; } pk;
  #pragma unroll
  for (int r = 0; r < 16; ++r) pk.u[r] = f2bf(acc[r] * ds[rb + r]);
  const size_t tile = ((size_t)(o >> 5) * 512 + (rb >> 4)) * 512;
  uint4* dst = (uint4*)(Vt + tile + (size_t)(o & 31) * 8);
  dst[0]  = pk.v[0];
  dst[32] = pk.v[1];
}

// ---------------------------------------------------------------------------
// prep_w: W (f32 [K=256][F]) -> bf16 fragment tiles Wt[(kt*F/32 + ct)].
// Frag: lane = (o&31)|(((k>>3)&1)<<5), elem = k&7. 192 blocks x 64 thr.
// ---------------------------------------------------------------------------
__global__ __launch_bounds__(64) void prep_w(
    const float* __restrict__ W2, const float* __restrict__ W3,
    u16* __restrict__ W2t, u16* __restrict__ W3t){
  const int b = blockIdx.x, l = threadIdx.x;
  const float* W; u16* Wt; int F, fi;
  if (b < 128){ W = W2; Wt = W2t; F = 256; fi = b; }
  else        { W = W3; Wt = W3t; F = 128; fi = b - 128; }
  const int CT = F / 32;
  const int kt = fi / CT, ct = fi % CT;
  const int o  = ct * 32 + (l & 31);
  const int kb = kt * 16 + (l >> 5) * 8;
  union { u16 u[8]; uint4 v; } pk;
  #pragma unroll
  for (int e = 0; e < 8; ++e) pk.u[e] = f2bf(W[(size_t)(kb + e) * F + o]);
  *(uint4*)(Wt + (size_t)fi * 512 + l * 8) = pk.v;
}

// ---------------------------------------------------------------------------
// small_mfma<F>: VT = (ds * H@W)^T tiled, H tiled bf16, W pre-tiled bf16.
// 256 blocks (32 rows each) x 256 thr; register-direct frags; zero LDS.
// Wave w covers col-tiles [w*CT, w*CT+CT).
// ---------------------------------------------------------------------------
template<int F>
__global__ __launch_bounds__(256) void small_mfma(
    const u16* __restrict__ Ht, const u16* __restrict__ Wt,
    const float* __restrict__ ds, u16* __restrict__ Vt){
  constexpr int CT = F / 128;           // col-tiles per wave (2 or 1)
  const int t = threadIdx.x, w = t >> 6, lane = t & 63;
  const int rowt = blockIdx.x;
  const u16* ha = Ht + ((size_t)rowt * 16) * 512 + lane * 8;
  const u16* wb = Wt + ((size_t)(w * CT)) * 512 + lane * 8;
  f32x16 acc[CT];
  #pragma unroll
  for (int ct = 0; ct < CT; ++ct)
    #pragma unroll
    for (int i = 0; i < 16; ++i) acc[ct][i] = 0.f;
  #pragma unroll
  for (int kt = 0; kt < 16; ++kt){
    bf16x8 a = *(const bf16x8*)(const void*)(ha + (size_t)kt * 512);
    #pragma unroll
    for (int ct = 0; ct < CT; ++ct){
      bf16x8 b = *(const bf16x8*)(const void*)(wb + (size_t)(kt * (F/32) + ct) * 512);
      acc[ct] = __builtin_amdgcn_mfma_f32_32x32x16_bf16(a, b, acc[ct], 0, 0, 0);
    }
  }
  const int rhi = (lane >> 5) << 2, cl = lane & 31;
  #pragma unroll
  for (int ct = 0; ct < CT; ++ct){
    const size_t obase = ((size_t)(w * CT + ct) * 512 + rowt * 2) * 512;
    #pragma unroll
    for (int r = 0; r < 16; ++r){
      const int rl = (r & 3) + ((r >> 2) << 3) + rhi;
      const int i  = rowt * 32 + rl;
      const u16 v = f2bf(acc[ct][r] * ds[i]);
      Vt[obase + (size_t)(rl >> 4) * 512 + (cl | (((rl >> 3) & 1) << 5)) * 8 + (rl & 7)] = v;
    }
  }
}

// ---------------------------------------------------------------------------
// F=256 big GEMM (R14 structure, measured 48us); H OUT IN TILED LAYOUT (R17).
// ---------------------------------------------------------------------------
__global__ __launch_bounds__(256) void gemm_rt(
    const u16* __restrict__ Ab, const u16* __restrict__ Vt,
    const float* __restrict__ ds, u16* __restrict__ Hout){
  __shared__ u16 Ls[2][32 * 512];        // 2 x 32KB
  const int t = threadIdx.x, w = t >> 6, lane = t & 63;
  const int rowg = blockIdx.x & 127;
  const int colg = blockIdx.x >> 7;      // 0..3

  const u16* sP0 = Ab + ((size_t)(rowg * 2 + 0) * 512) * 512 + lane * 8;
  const u16* sP1 = Ab + ((size_t)(rowg * 2 + 1) * 512) * 512 + lane * 8;
  const u16* sP2 = Vt + ((size_t)(colg * 2 + 0) * 512) * 512 + lane * 8;
  const u16* sP3 = Vt + ((size_t)(colg * 2 + 1) * 512) * 512 + lane * 8;

  f32x16 a00, a01, a10, a11;
  #pragma unroll
  for (int i = 0; i < 16; ++i){ a00[i]=0.f; a01[i]=0.f; a10[i]=0.f; a11[i]=0.f; }

  auto stage = [&](int buf, int c){
    u16* L = &Ls[buf][0] + lane * 8;
    #pragma unroll
    for (int h = 0; h < 2; ++h){
      const int kt = c * 8 + h * 4 + w;
      const int sl = h * 4 + w;
      const size_t so = (size_t)kt * 512;
      __builtin_amdgcn_global_load_lds(
        (const __attribute__((address_space(1))) u32*)(sP0 + so),
        (__attribute__((address_space(3))) u32*)(L + (0  + sl) * 512), 16, 0, 0);
      __builtin_amdgcn_global_load_lds(
        (const __attribute__((address_space(1))) u32*)(sP1 + so),
        (__attribute__((address_space(3))) u32*)(L + (8  + sl) * 512), 16, 0, 0);
      __builtin_amdgcn_global_load_lds(
        (const __attribute__((address_space(1))) u32*)(sP2 + so),
        (__attribute__((address_space(3))) u32*)(L + (16 + sl) * 512), 16, 0, 0);
      __builtin_amdgcn_global_load_lds(
        (const __attribute__((address_space(1))) u32*)(sP3 + so),
        (__attribute__((address_space(3))) u32*)(L + (24 + sl) * 512), 16, 0, 0);
    }
  };
  auto compute = [&](int buf){
    const u16* L = &Ls[buf][0] + lane * 8;
    #pragma unroll
    for (int h = 0; h < 2; ++h){
      const int sl = h * 4 + w;
      bf16x8 fa0 = *(const bf16x8*)(const void*)(L + (0  + sl) * 512);
      bf16x8 fa1 = *(const bf16x8*)(const void*)(L + (8  + sl) * 512);
      bf16x8 fb0 = *(const bf16x8*)(const void*)(L + (16 + sl) * 512);
      bf16x8 fb1 = *(const bf16x8*)(const void*)(L + (24 + sl) * 512);
      a00 = __builtin_amdgcn_mfma_f32_32x32x16_bf16(fa0, fb0, a00, 0, 0, 0);
      a01 = __builtin_amdgcn_mfma_f32_32x32x16_bf16(fa0, fb1, a01, 0, 0, 0);
      a10 = __builtin_amdgcn_mfma_f32_32x32x16_bf16(fa1, fb0, a10, 0, 0, 0);
      a11 = __builtin_amdgcn_mfma_f32_32x32x16_bf16(fa1, fb1, a11, 0, 0, 0);
    }
  };

  stage(0, 0);
  __syncthreads();
  for (int c = 0; c < 64; ++c){
    if (c < 63) stage((c + 1) & 1, c + 1);
    compute(c & 1);
    __syncthreads();
  }

  // ---- tree-reduce the 4 wave-partials (reuse Ls as f32 scratch) ----
  float* Rf = (float*)(&Ls[0][0]);
  f32x16 aq[4];
  aq[0] = a00; aq[1] = a01; aq[2] = a10; aq[3] = a11;
  if (w >= 2){
    float* o = Rf + (w - 2) * 4096 + lane;
    #pragma unroll
    for (int q = 0; q < 4; ++q)
      #pragma unroll
      for (int r = 0; r < 16; ++r)
        o[(q * 16 + r) * 64] = aq[q][r];
  }
  __syncthreads();
  if (w < 2){
    const float* o = Rf + w * 4096 + lane;
    #pragma unroll
    for (int q = 0; q < 4; ++q)
      #pragma unroll
      for (int r = 0; r < 16; ++r)
        aq[q][r] += o[(q * 16 + r) * 64];
  }
  __syncthreads();
  if (w == 1){
    float* o = Rf + lane;
    #pragma unroll
    for (int q = 0; q < 4; ++q)
      #pragma unroll
      for (int r = 0; r < 16; ++r)
        o[(q * 16 + r) * 64] = aq[q][r];
  }
  __syncthreads();
  if (w == 0){
    const float* o = Rf + lane;
    const int rhi = (lane >> 5) << 2;
    const int cl  = lane & 31;
    #pragma unroll
    for (int q = 0; q < 4; ++q){
      const int rowtile = rowg * 2 + (q >> 1);
      const int ct16    = colg * 4 + (q & 1) * 2 + (cl >> 4);  // 16-col k-tile
      #pragma unroll
      for (int r = 0; r < 16; ++r){
        const int rl = (r & 3) + ((r >> 2) << 3) + rhi;
        const int row = rowg * 64 + (q >> 1) * 32 + rl;
        float v = aq[q][r] + o[(q * 16 + r) * 64];
        v *= ds[row];
        v = fmaxf(v, 0.f);
        // tiled H store: tile (row>>5, col>>4)
        Hout[((size_t)rowtile * 16 + ct16) * 512
             + (rl | (((cl >> 3) & 1) << 5)) * 8 + (cl & 7)] = f2bf(v);
      }
    }
  }
}

// ---------------------------------------------------------------------------
// F=128 big GEMM (R16 LDS structure): 32x64 tiles, f32 row-major out.
// ---------------------------------------------------------------------------
__global__ __launch_bounds__(256) void gemm_rt128(
    const u16* __restrict__ Ab, const u16* __restrict__ Vt,
    const float* __restrict__ ds, float* __restrict__ Fout){
  __shared__ u16 Ls[2][24 * 512];
  const int t = threadIdx.x, w = t >> 6, lane = t & 63;
  const int rowg = blockIdx.x & 255;
  const int colg = blockIdx.x >> 8;

  const u16* sA  = Ab + ((size_t)rowg * 512) * 512 + lane * 8;
  const u16* sB0 = Vt + ((size_t)(colg * 2 + 0) * 512) * 512 + lane * 8;
  const u16* sB1 = Vt + ((size_t)(colg * 2 + 1) * 512) * 512 + lane * 8;

  f32x16 p0, p1;
  #pragma unroll
  for (int i = 0; i < 16; ++i){ p0[i] = 0.f; p1[i] = 0.f; }

  auto stage = [&](int buf, int c){
    u16* L = &Ls[buf][0] + lane * 8;
    #pragma unroll
    for (int h = 0; h < 2; ++h){
      const int kt = c * 8 + h * 4 + w;
      const int sl = h * 4 + w;
      const size_t so = (size_t)kt * 512;
      __builtin_amdgcn_global_load_lds(
        (const __attribute__((address_space(1))) u32*)(sA + so),
        (__attribute__((address_space(3))) u32*)(L + (0  + sl) * 512), 16, 0, 0);
      __builtin_amdgcn_global_load_lds(
        (const __attribute__((address_space(1))) u32*)(sB0 + so),
        (__attribute__((address_space(3))) u32*)(L + (8  + sl) * 512), 16, 0, 0);
      __builtin_amdgcn_global_load_lds(
        (const __attribute__((address_space(1))) u32*)(sB1 + so),
        (__attribute__((address_space(3))) u32*)(L + (16 + sl) * 512), 16, 0, 0);
    }
  };
  auto compute = [&](int buf){
    const u16* L = &Ls[buf][0] + lane * 8;
    #pragma unroll
    for (int h = 0; h < 2; ++h){
      const int sl = h * 4 + w;
      bf16x8 fa  = *(const bf16x8*)(const void*)(L + (0  + sl) * 512);
      bf16x8 fb0 = *(const bf16x8*)(const void*)(L + (8  + sl) * 512);
      bf16x8 fb1 = *(const bf16x8*)(const void*)(L + (16 + sl) * 512);
      p0 = __builtin_amdgcn_mfma_f32_32x32x16_bf16(fa, fb0, p0, 0, 0, 0);
      p1 = __builtin_amdgcn_mfma_f32_32x32x16_bf16(fa, fb1, p1, 0, 0, 0);
    }
  };

  stage(0, 0);
  __syncthreads();
  for (int c = 0; c < 64; ++c){
    if (c < 63) stage((c + 1) & 1, c + 1);
    compute(c & 1);
    __syncthreads();
  }

  float* Rf = (float*)(&Ls[0][0]);
  f32x16 aq[2];
  aq[0] = p0; aq[1] = p1;
  if (w >= 2){
    float* o = Rf + (w - 2) * 2048 + lane;
    #pragma unroll
    for (int q = 0; q < 2; ++q)
      #pragma unroll
      for (int r = 0; r < 16; ++r)
        o[(q * 16 + r) * 64] = aq[q][r];
  }
  __syncthreads();
  if (w < 2){
    const float* o = Rf + w * 2048 + lane;
    #pragma unroll
    for (int q = 0; q < 2; ++q)
      #pragma unroll
      for (int r = 0; r < 16; ++r)
        aq[q][r] += o[(q * 16 + r) * 64];
  }
  __syncthreads();
  if (w == 1){
    float* o = Rf + lane;
    #pragma unroll
    for (int q = 0; q < 2; ++q)
      #pragma unroll
      for (int r = 0; r < 16; ++r)
        o[(q * 16 + r) * 64] = aq[q][r];
  }
  __syncthreads();
  if (w == 0){
    const float* o = Rf + lane;
    const int rhi = (lane >> 5) << 2;
    const int cl  = lane & 31;
    #pragma unroll
    for (int q = 0; q < 2; ++q){
      const int cbase = colg * 64 + q * 32;
      #pragma unroll
      for (int r = 0; r < 16; ++r){
        const int rl = (r & 3) + ((r >> 2) << 3) + rhi;
        const int row = rowg * 32 + rl;
        float v = aq[q][r] + o[(q * 16 + r) * 64];
        Fout[(size_t)row * 128 + cbase + cl] = v * ds[row];
      }
    }
  }
}

// ---------------------------------------------------------------------------
// Attention scores: sc[i] = tanh(Z[i,:] @ Wl^T + bl) @ q + b
// ---------------------------------------------------------------------------
__device__ __forceinline__ float tanh_fast(float x){
  x = fminf(fmaxf(x, -15.f), 15.f);
  float e = __expf(2.f * x);
  return (e - 1.f) / (e + 1.f);
}

__global__ __launch_bounds__(256) void attn_scores(
    const float* __restrict__ Z, const float* __restrict__ Wl,
    const float* __restrict__ bl, const float* __restrict__ q,
    const float* __restrict__ bsc, float* __restrict__ sc){
  __shared__ float wl[128 * 128];          // 64 KiB exactly, swizzled
  const int t = threadIdx.x, lane = t & 63, wave = t >> 6;
  for (int j = 0; j < 64; ++j){
    int idx = j * 256 + t;
    int o = idx >> 7, k = idx & 127;
    int c = k >> 2, e = k & 3;
    wl[o * 128 + (((c ^ (o & 31)) << 2) | e)] = Wl[idx];
  }
  __syncthreads();
  const float bl0 = bl[lane], bl1 = bl[lane + 64];
  const float q0  = q[lane],  q1  = q[lane + 64];
  const float bb  = bsc[0];
  const int r0 = blockIdx.x * 16;
  for (int rr = 0; rr < 4; ++rr){
    int r = r0 + wave * 4 + rr;
    float d0 = 0.f, d1 = 0.f;
    #pragma unroll
    for (int c = 0; c < 32; ++c){
      float4 zv = *(const float4*)(Z + (size_t)r * 128 + c * 4);
      float4 w0 = *(const float4*)&wl[ lane      * 128 + ((c ^ (lane & 31)) << 2)];
      float4 w1 = *(const float4*)&wl[(lane + 64)* 128 + ((c ^ (lane & 31)) << 2)];
      d0 += zv.x*w0.x + zv.y*w0.y + zv.z*w0.z + zv.w*w0.w;
      d1 += zv.x*w1.x + zv.y*w1.y + zv.z*w1.z + zv.w*w1.w;
    }
    float s = tanh_fast(d0 + bl0) * q0 + tanh_fast(d1 + bl1) * q1;
    #pragma unroll
    for (int off = 32; off > 0; off >>= 1) s += __shfl_down(s, off, 64);
    if (lane == 0) sc[r] = s + bb;
  }
}

__global__ __launch_bounds__(1024) void softmax_red(
    const float* __restrict__ sc, float* __restrict__ sred){
  const int t = threadIdx.x, lane = t & 63, wave = t >> 6;
  __shared__ float red[16];
  float m = -1e30f;
  for (int i = t; i < 8192; i += 1024) m = fmaxf(m, sc[i]);
  #pragma unroll
  for (int off = 32; off > 0; off >>= 1) m = fmaxf(m, __shfl_down(m, off, 64));
  if (lane == 0) red[wave] = m;
  __syncthreads();
  if (t == 0){
    float mm = red[0];
    for (int w = 1; w < 16; ++w) mm = fmaxf(mm, red[w]);
    red[0] = mm;
  }
  __syncthreads();
  const float bmax = red[0];
  __syncthreads();
  float s = 0.f;
  for (int i = t; i < 8192; i += 1024) s += __expf(sc[i] - bmax);
  #pragma unroll
  for (int off = 32; off > 0; off >>= 1) s += __shfl_down(s, off, 64);
  if (lane == 0) red[wave] = s;
  __syncthreads();
  if (t == 0){
    float ss = 0.f;
    for (int w = 0; w < 16; ++w) ss += red[w];
    sred[0] = bmax; sred[1] = ss;
  }
}

__global__ __launch_bounds__(256) void weighted_part(
    const float* __restrict__ sc, const float* __restrict__ sred,
    const float* __restrict__ Z, float* __restrict__ part){
  const int blk = blockIdx.x, t = threadIdx.x;
  const int o = t & 127, h = t >> 7;
  const float bmax = sred[0], inv = 1.f / sred[1];
  float acc = 0.f;
  const int i0 = blk * 128;
  for (int i = i0 + h; i < i0 + 128; i += 2){
    float w = __expf(sc[i] - bmax) * inv;
    acc += w * Z[(size_t)i * 128 + o];
  }
  __shared__ float l[256];
  l[t] = acc;
  __syncthreads();
  if (h == 0) part[blk * 128 + o] = l[o] + l[o + 128];
}

__global__ __launch_bounds__(128) void final_red(
    const float* __restrict__ part, float* __restrict__ out){
  const int o = threadIdx.x;
  float s = 0.f;
  for (int b = 0; b < 64; ++b) s += part[b * 128 + o];
  out[o] = s;
}

// ---------------------------------------------------------------------------
extern "C" void kernel_launch(void* const* d_in, const int* in_sizes, int n_in,
                              void* d_out, int out_size, void* d_ws, size_t ws_size,
                              hipStream_t stream){
  const float* x  = (const float*)d_in[0];
  const float* A  = (const float*)d_in[1];
  const float* W1 = (const float*)d_in[2];
  const float* W2 = (const float*)d_in[3];
  const float* W3 = (const float*)d_in[4];
  const float* Wl = (const float*)d_in[5];
  const float* bl = (const float*)d_in[6];
  const float* q  = (const float*)d_in[7];
  const float* b  = (const float*)d_in[8];
  float* out = (float*)d_out;
  char* ws = (char*)d_ws;

  u16*   AB   = (u16*)(ws);                      // 128 MiB, tiled
  float* DS   = (float*)(ws + 134217728);        // 32 KiB
  u16*   VT   = (u16*)(ws + 134250496);          // 4 MiB, tiled
  u16*   HB   = (u16*)(ws + 138444800);          // 4 MiB, TILED (R17)
  float* SC   = (float*)(ws + 142639104);        // 8192 f32 scores
  float* SP   = (float*)(ws + 142671872);        // 64*128 f32
  float* SRED = (float*)(ws + 142704640);        // {max, sumexp}
  u16*   W2T  = (u16*)(ws + 142705664);          // 128 KiB tiled W2
  u16*   W3T  = (u16*)(ws + 142836736);          // 64 KiB tiled W3

  rowsum_tileA<<<256, 1024, 0, stream>>>(A, AB, DS);
  prep_w<<<192, 64, 0, stream>>>(W2, W3, W2T, W3T);
  // layer 1
  small_gemm<128, 256><<<512, 256, 0, stream>>>(x, W1, DS, VT);
  gemm_rt<<<512, 256, 0, stream>>>(AB, VT, DS, HB);
  // layer 2
  small_mfma<256><<<256, 256, 0, stream>>>(HB, W2T, DS, VT);
  gemm_rt<<<512, 256, 0, stream>>>(AB, VT, DS, HB);
  // layer 3 -> z_context f32 straight into d_out
  small_mfma<128><<<256, 256, 0, stream>>>(HB, W3T, DS, VT);
  gemm_rt128<<<512, 256, 0, stream>>>(AB, VT, DS, out);
  // attention pooling
  attn_scores<<<512, 256, 0, stream>>>(out, Wl, bl, q, b, SC);
  softmax_red<<<1, 1024, 0, stream>>>(SC, SRED);
  weighted_part<<<64, 256, 0, stream>>>(SC, SRED, out, SP);
  final_red<<<1, 128, 0, stream>>>(SP, out + 8192 * 128);
}

// Round 18
// 288.336 us; speedup vs baseline: 1.8200x; 1.0678x over previous
//
#include <hip/hip_runtime.h>

typedef unsigned short u16;
typedef unsigned int   u32;
typedef __bf16 bf16x8 __attribute__((ext_vector_type(8)));
typedef float  f32x16 __attribute__((ext_vector_type(16)));

__device__ __forceinline__ u16 f2bf(float f){
  u32 u = __float_as_uint(f);
  u32 r = (u + 0x7FFFu + ((u >> 16) & 1u)) >> 16;   // RNE
  return (u16)r;
}

// ===========================================================================
// TILED OPERAND LAYOUT (validated R8): tile = 32 rows x 16 k = 1KB,
// elem (row,k) -> tile (row>>5, k>>4), lane = (row&31)|(((k>>3)&1)<<5),
// byte = tile*1024 + lane*16 + (k&7)*2. Contiguous, lane-ordered.
//
// R17 post-mortem: MFMA-izing small gemms 2,3 = -69us (redundancy audit was
// right). R18: (1) layer-1 small -> MFMA too (prep_x tiles x as bf16, prep_w
// also tiles W1, small_mfma<F,KT> with KT=8); (2) rowsum double-buffered
// LDS -> ONE barrier per chunk (was 2 full drains x 64 chunks at 1 blk/CU).
// ===========================================================================

// ---------------------------------------------------------------------------
// Pass 1: row sums + f32->bf16 + transpose to tiled layout via LDS.
// Double-buffered: write buf[c&1] -> barrier -> copy-out (overlaps next reads).
// ---------------------------------------------------------------------------
__global__ __launch_bounds__(1024) void rowsum_tileA(
    const float* __restrict__ A, u16* __restrict__ Ab, float* __restrict__ ds){
  __shared__ u16 lt[2][8192];            // 2 x 16 KB
  const int t = threadIdx.x;
  const int r = t >> 5, q = t & 31;      // row 0..31, 32 threads/row
  const int rg = blockIdx.x;
  const float* ar = A + ((size_t)rg * 32 + r) * 8192;
  float s = 0.f;
  for (int ch = 0; ch < 32; ++ch){
    u16* lb = lt[ch & 1];
    #pragma unroll
    for (int j = 0; j < 2; ++j){
      const int c4 = ch * 64 + j * 32 + q;           // float4 col index
      float4 v = ((const float4*)ar)[c4];
      s += (v.x + v.y) + (v.z + v.w);
      const int cl = (j * 32 + q) * 4;               // local col 0..255
      const int tile = cl >> 4;
      const int tl   = (r | (((cl >> 3) & 1) << 5)) ^ (tile & 7);  // swizzled
      const int idx  = tile * 512 + tl * 8 + (cl & 7);
      ushort4 o;
      o.x = f2bf(v.x); o.y = f2bf(v.y); o.z = f2bf(v.z); o.w = f2bf(v.w);
      *(ushort4*)(lb + idx) = o;
    }
    __syncthreads();
    {
      const int tile = t >> 6, tl = t & 63;          // un-swizzle on read
      uint4 v = *(const uint4*)(lb + tile * 512 + (tl ^ (tile & 7)) * 8);
      uint4* dst = (uint4*)(Ab + ((size_t)rg * 512 + ch * 16) * 512);
      dst[t] = v;
    }
    // no second barrier: next chunk writes the OTHER buffer; chunk c+2's
    // writes are fenced by barrier(c+1) which drains this copy-out's ds_reads.
  }
  #pragma unroll
  for (int m = 16; m > 0; m >>= 1) s += __shfl_xor(s, m, 64);
  if (q == 0) ds[rg * 32 + r] = rsqrtf(s);
}

// ---------------------------------------------------------------------------
// prep_x: x f32 [8192][128] -> tiled bf16 Xt (row-tile stride 8 k-tiles).
// 256 blocks x 1024 thr; same LDS-transpose trick, single chunk.
// ---------------------------------------------------------------------------
__global__ __launch_bounds__(1024) void prep_x(
    const float* __restrict__ x, u16* __restrict__ Xt){
  __shared__ u16 lt[4096];               // 8 tiles x 512 u16 = 8 KB
  const int t = threadIdx.x;
  const int r = t >> 5, q = t & 31;
  const int rg = blockIdx.x;
  float4 v = ((const float4*)(x + ((size_t)rg * 32 + r) * 128))[q];
  const int cl = q * 4;                  // local col 0..127
  const int tile = cl >> 4;              // 0..7
  const int tl   = (r | (((cl >> 3) & 1) << 5)) ^ (tile & 7);
  ushort4 o;
  o.x = f2bf(v.x); o.y = f2bf(v.y); o.z = f2bf(v.z); o.w = f2bf(v.w);
  *(ushort4*)(lt + tile * 512 + tl * 8 + (cl & 7)) = o;
  __syncthreads();
  if (t < 512){
    const int tile2 = t >> 6, tl2 = t & 63;
    uint4 w = *(const uint4*)(lt + tile2 * 512 + (tl2 ^ (tile2 & 7)) * 8);
    ((uint4*)(Xt + (size_t)rg * 4096))[t] = w;
  }
}

// ---------------------------------------------------------------------------
// prep_w: W1/W2/W3 f32 -> bf16 fragment tiles (fi = kt*(F/32) + ct).
// 256 blocks x 64 thr: b<64 -> W1 (K=128,F=256); b<192 -> W2; else W3.
// ---------------------------------------------------------------------------
__global__ __launch_bounds__(64) void prep_w(
    const float* __restrict__ W1, const float* __restrict__ W2,
    const float* __restrict__ W3, u16* __restrict__ W1t,
    u16* __restrict__ W2t, u16* __restrict__ W3t){
  const int b = blockIdx.x, l = threadIdx.x;
  const float* W; u16* Wt; int F, fi;
  if (b < 64)       { W = W1; Wt = W1t; F = 256; fi = b; }
  else if (b < 192) { W = W2; Wt = W2t; F = 256; fi = b - 64; }
  else              { W = W3; Wt = W3t; F = 128; fi = b - 192; }
  const int CT = F / 32;
  const int kt = fi / CT, ct = fi % CT;
  const int o  = ct * 32 + (l & 31);
  const int kb = kt * 16 + (l >> 5) * 8;
  union { u16 u[8]; uint4 v; } pk;
  #pragma unroll
  for (int e = 0; e < 8; ++e) pk.u[e] = f2bf(W[(size_t)(kb + e) * F + o]);
  *(uint4*)(Wt + (size_t)fi * 512 + l * 8) = pk.v;
}

// ---------------------------------------------------------------------------
// small_mfma<F,KT>: VT = (ds * H@W)^T tiled. H tiled bf16 (KT k-tiles/row-
// tile), W pre-tiled bf16. 256 blocks x 256 thr; register-direct; zero LDS.
// ---------------------------------------------------------------------------
template<int F, int KT>
__global__ __launch_bounds__(256) void small_mfma(
    const u16* __restrict__ Ht, const u16* __restrict__ Wt,
    const float* __restrict__ ds, u16* __restrict__ Vt){
  constexpr int CT = F / 128;           // col-tiles per wave (2 or 1)
  const int t = threadIdx.x, w = t >> 6, lane = t & 63;
  const int rowt = blockIdx.x;
  const u16* ha = Ht + ((size_t)rowt * KT) * 512 + lane * 8;
  const u16* wb = Wt + ((size_t)(w * CT)) * 512 + lane * 8;
  f32x16 acc[CT];
  #pragma unroll
  for (int ct = 0; ct < CT; ++ct)
    #pragma unroll
    for (int i = 0; i < 16; ++i) acc[ct][i] = 0.f;
  #pragma unroll
  for (int kt = 0; kt < KT; ++kt){
    bf16x8 a = *(const bf16x8*)(const void*)(ha + (size_t)kt * 512);
    #pragma unroll
    for (int ct = 0; ct < CT; ++ct){
      bf16x8 b = *(const bf16x8*)(const void*)(wb + (size_t)(kt * (F/32) + ct) * 512);
      acc[ct] = __builtin_amdgcn_mfma_f32_32x32x16_bf16(a, b, acc[ct], 0, 0, 0);
    }
  }
  const int rhi = (lane >> 5) << 2, cl = lane & 31;
  #pragma unroll
  for (int ct = 0; ct < CT; ++ct){
    const size_t obase = ((size_t)(w * CT + ct) * 512 + rowt * 2) * 512;
    #pragma unroll
    for (int r = 0; r < 16; ++r){
      const int rl = (r & 3) + ((r >> 2) << 3) + rhi;
      const int i  = rowt * 32 + rl;
      const u16 v = f2bf(acc[ct][r] * ds[i]);
      Vt[obase + (size_t)(rl >> 4) * 512 + (cl | (((rl >> 3) & 1) << 5)) * 8 + (rl & 7)] = v;
    }
  }
}

// ---------------------------------------------------------------------------
// F=256 big GEMM (R14 structure, measured 48us); H out in tiled layout.
// ---------------------------------------------------------------------------
__global__ __launch_bounds__(256) void gemm_rt(
    const u16* __restrict__ Ab, const u16* __restrict__ Vt,
    const float* __restrict__ ds, u16* __restrict__ Hout){
  __shared__ u16 Ls[2][32 * 512];        // 2 x 32KB
  const int t = threadIdx.x, w = t >> 6, lane = t & 63;
  const int rowg = blockIdx.x & 127;
  const int colg = blockIdx.x >> 7;      // 0..3

  const u16* sP0 = Ab + ((size_t)(rowg * 2 + 0) * 512) * 512 + lane * 8;
  const u16* sP1 = Ab + ((size_t)(rowg * 2 + 1) * 512) * 512 + lane * 8;
  const u16* sP2 = Vt + ((size_t)(colg * 2 + 0) * 512) * 512 + lane * 8;
  const u16* sP3 = Vt + ((size_t)(colg * 2 + 1) * 512) * 512 + lane * 8;

  f32x16 a00, a01, a10, a11;
  #pragma unroll
  for (int i = 0; i < 16; ++i){ a00[i]=0.f; a01[i]=0.f; a10[i]=0.f; a11[i]=0.f; }

  auto stage = [&](int buf, int c){
    u16* L = &Ls[buf][0] + lane * 8;
    #pragma unroll
    for (int h = 0; h < 2; ++h){
      const int kt = c * 8 + h * 4 + w;
      const int sl = h * 4 + w;
      const size_t so = (size_t)kt * 512;
      __builtin_amdgcn_global_load_lds(
        (const __attribute__((address_space(1))) u32*)(sP0 + so),
        (__attribute__((address_space(3))) u32*)(L + (0  + sl) * 512), 16, 0, 0);
      __builtin_amdgcn_global_load_lds(
        (const __attribute__((address_space(1))) u32*)(sP1 + so),
        (__attribute__((address_space(3))) u32*)(L + (8  + sl) * 512), 16, 0, 0);
      __builtin_amdgcn_global_load_lds(
        (const __attribute__((address_space(1))) u32*)(sP2 + so),
        (__attribute__((address_space(3))) u32*)(L + (16 + sl) * 512), 16, 0, 0);
      __builtin_amdgcn_global_load_lds(
        (const __attribute__((address_space(1))) u32*)(sP3 + so),
        (__attribute__((address_space(3))) u32*)(L + (24 + sl) * 512), 16, 0, 0);
    }
  };
  auto compute = [&](int buf){
    const u16* L = &Ls[buf][0] + lane * 8;
    #pragma unroll
    for (int h = 0; h < 2; ++h){
      const int sl = h * 4 + w;
      bf16x8 fa0 = *(const bf16x8*)(const void*)(L + (0  + sl) * 512);
      bf16x8 fa1 = *(const bf16x8*)(const void*)(L + (8  + sl) * 512);
      bf16x8 fb0 = *(const bf16x8*)(const void*)(L + (16 + sl) * 512);
      bf16x8 fb1 = *(const bf16x8*)(const void*)(L + (24 + sl) * 512);
      a00 = __builtin_amdgcn_mfma_f32_32x32x16_bf16(fa0, fb0, a00, 0, 0, 0);
      a01 = __builtin_amdgcn_mfma_f32_32x32x16_bf16(fa0, fb1, a01, 0, 0, 0);
      a10 = __builtin_amdgcn_mfma_f32_32x32x16_bf16(fa1, fb0, a10, 0, 0, 0);
      a11 = __builtin_amdgcn_mfma_f32_32x32x16_bf16(fa1, fb1, a11, 0, 0, 0);
    }
  };

  stage(0, 0);
  __syncthreads();
  for (int c = 0; c < 64; ++c){
    if (c < 63) stage((c + 1) & 1, c + 1);
    compute(c & 1);
    __syncthreads();
  }

  // ---- tree-reduce the 4 wave-partials (reuse Ls as f32 scratch) ----
  float* Rf = (float*)(&Ls[0][0]);
  f32x16 aq[4];
  aq[0] = a00; aq[1] = a01; aq[2] = a10; aq[3] = a11;
  if (w >= 2){
    float* o = Rf + (w - 2) * 4096 + lane;
    #pragma unroll
    for (int q = 0; q < 4; ++q)
      #pragma unroll
      for (int r = 0; r < 16; ++r)
        o[(q * 16 + r) * 64] = aq[q][r];
  }
  __syncthreads();
  if (w < 2){
    const float* o = Rf + w * 4096 + lane;
    #pragma unroll
    for (int q = 0; q < 4; ++q)
      #pragma unroll
      for (int r = 0; r < 16; ++r)
        aq[q][r] += o[(q * 16 + r) * 64];
  }
  __syncthreads();
  if (w == 1){
    float* o = Rf + lane;
    #pragma unroll
    for (int q = 0; q < 4; ++q)
      #pragma unroll
      for (int r = 0; r < 16; ++r)
        o[(q * 16 + r) * 64] = aq[q][r];
  }
  __syncthreads();
  if (w == 0){
    const float* o = Rf + lane;
    const int rhi = (lane >> 5) << 2;
    const int cl  = lane & 31;
    #pragma unroll
    for (int q = 0; q < 4; ++q){
      const int rowtile = rowg * 2 + (q >> 1);
      const int ct16    = colg * 4 + (q & 1) * 2 + (cl >> 4);
      #pragma unroll
      for (int r = 0; r < 16; ++r){
        const int rl = (r & 3) + ((r >> 2) << 3) + rhi;
        const int row = rowg * 64 + (q >> 1) * 32 + rl;
        float v = aq[q][r] + o[(q * 16 + r) * 64];
        v *= ds[row];
        v = fmaxf(v, 0.f);
        Hout[((size_t)rowtile * 16 + ct16) * 512
             + (rl | (((cl >> 3) & 1) << 5)) * 8 + (cl & 7)] = f2bf(v);
      }
    }
  }
}

// ---------------------------------------------------------------------------
// F=128 big GEMM (R16 LDS structure): 32x64 tiles, f32 row-major out.
// ---------------------------------------------------------------------------
__global__ __launch_bounds__(256) void gemm_rt128(
    const u16* __restrict__ Ab, const u16* __restrict__ Vt,
    const float* __restrict__ ds, float* __restrict__ Fout){
  __shared__ u16 Ls[2][24 * 512];
  const int t = threadIdx.x, w = t >> 6, lane = t & 63;
  const int rowg = blockIdx.x & 255;
  const int colg = blockIdx.x >> 8;

  const u16* sA  = Ab + ((size_t)rowg * 512) * 512 + lane * 8;
  const u16* sB0 = Vt + ((size_t)(colg * 2 + 0) * 512) * 512 + lane * 8;
  const u16* sB1 = Vt + ((size_t)(colg * 2 + 1) * 512) * 512 + lane * 8;

  f32x16 p0, p1;
  #pragma unroll
  for (int i = 0; i < 16; ++i){ p0[i] = 0.f; p1[i] = 0.f; }

  auto stage = [&](int buf, int c){
    u16* L = &Ls[buf][0] + lane * 8;
    #pragma unroll
    for (int h = 0; h < 2; ++h){
      const int kt = c * 8 + h * 4 + w;
      const int sl = h * 4 + w;
      const size_t so = (size_t)kt * 512;
      __builtin_amdgcn_global_load_lds(
        (const __attribute__((address_space(1))) u32*)(sA + so),
        (__attribute__((address_space(3))) u32*)(L + (0  + sl) * 512), 16, 0, 0);
      __builtin_amdgcn_global_load_lds(
        (const __attribute__((address_space(1))) u32*)(sB0 + so),
        (__attribute__((address_space(3))) u32*)(L + (8  + sl) * 512), 16, 0, 0);
      __builtin_amdgcn_global_load_lds(
        (const __attribute__((address_space(1))) u32*)(sB1 + so),
        (__attribute__((address_space(3))) u32*)(L + (16 + sl) * 512), 16, 0, 0);
    }
  };
  auto compute = [&](int buf){
    const u16* L = &Ls[buf][0] + lane * 8;
    #pragma unroll
    for (int h = 0; h < 2; ++h){
      const int sl = h * 4 + w;
      bf16x8 fa  = *(const bf16x8*)(const void*)(L + (0  + sl) * 512);
      bf16x8 fb0 = *(const bf16x8*)(const void*)(L + (8  + sl) * 512);
      bf16x8 fb1 = *(const bf16x8*)(const void*)(L + (16 + sl) * 512);
      p0 = __builtin_amdgcn_mfma_f32_32x32x16_bf16(fa, fb0, p0, 0, 0, 0);
      p1 = __builtin_amdgcn_mfma_f32_32x32x16_bf16(fa, fb1, p1, 0, 0, 0);
    }
  };

  stage(0, 0);
  __syncthreads();
  for (int c = 0; c < 64; ++c){
    if (c < 63) stage((c + 1) & 1, c + 1);
    compute(c & 1);
    __syncthreads();
  }

  float* Rf = (float*)(&Ls[0][0]);
  f32x16 aq[2];
  aq[0] = p0; aq[1] = p1;
  if (w >= 2){
    float* o = Rf + (w - 2) * 2048 + lane;
    #pragma unroll
    for (int q = 0; q < 2; ++q)
      #pragma unroll
      for (int r = 0; r < 16; ++r)
        o[(q * 16 + r) * 64] = aq[q][r];
  }
  __syncthreads();
  if (w < 2){
    const float* o = Rf + w * 2048 + lane;
    #pragma unroll
    for (int q = 0; q < 2; ++q)
      #pragma unroll
      for (int r = 0; r < 16; ++r)
        aq[q][r] += o[(q * 16 + r) * 64];
  }
  __syncthreads();
  if (w == 1){
    float* o = Rf + lane;
    #pragma unroll
    for (int q = 0; q < 2; ++q)
      #pragma unroll
      for (int r = 0; r < 16; ++r)
        o[(q * 16 + r) * 64] = aq[q][r];
  }
  __syncthreads();
  if (w == 0){
    const float* o = Rf + lane;
    const int rhi = (lane >> 5) << 2;
    const int cl  = lane & 31;
    #pragma unroll
    for (int q = 0; q < 2; ++q){
      const int cbase = colg * 64 + q * 32;
      #pragma unroll
      for (int r = 0; r < 16; ++r){
        const int rl = (r & 3) + ((r >> 2) << 3) + rhi;
        const int row = rowg * 32 + rl;
        float v = aq[q][r] + o[(q * 16 + r) * 64];
        Fout[(size_t)row * 128 + cbase + cl] = v * ds[row];
      }
    }
  }
}

// ---------------------------------------------------------------------------
// Attention scores: sc[i] = tanh(Z[i,:] @ Wl^T + bl) @ q + b
// ---------------------------------------------------------------------------
__device__ __forceinline__ float tanh_fast(float x){
  x = fminf(fmaxf(x, -15.f), 15.f);
  float e = __expf(2.f * x);
  return (e - 1.f) / (e + 1.f);
}

__global__ __launch_bounds__(256) void attn_scores(
    const float* __restrict__ Z, const float* __restrict__ Wl,
    const float* __restrict__ bl, const float* __restrict__ q,
    const float* __restrict__ bsc, float* __restrict__ sc){
  __shared__ float wl[128 * 128];          // 64 KiB exactly, swizzled
  const int t = threadIdx.x, lane = t & 63, wave = t >> 6;
  for (int j = 0; j < 64; ++j){
    int idx = j * 256 + t;
    int o = idx >> 7, k = idx & 127;
    int c = k >> 2, e = k & 3;
    wl[o * 128 + (((c ^ (o & 31)) << 2) | e)] = Wl[idx];
  }
  __syncthreads();
  const float bl0 = bl[lane], bl1 = bl[lane + 64];
  const float q0  = q[lane],  q1  = q[lane + 64];
  const float bb  = bsc[0];
  const int r0 = blockIdx.x * 16;
  for (int rr = 0; rr < 4; ++rr){
    int r = r0 + wave * 4 + rr;
    float d0 = 0.f, d1 = 0.f;
    #pragma unroll
    for (int c = 0; c < 32; ++c){
      float4 zv = *(const float4*)(Z + (size_t)r * 128 + c * 4);
      float4 w0 = *(const float4*)&wl[ lane      * 128 + ((c ^ (lane & 31)) << 2)];
      float4 w1 = *(const float4*)&wl[(lane + 64)* 128 + ((c ^ (lane & 31)) << 2)];
      d0 += zv.x*w0.x + zv.y*w0.y + zv.z*w0.z + zv.w*w0.w;
      d1 += zv.x*w1.x + zv.y*w1.y + zv.z*w1.z + zv.w*w1.w;
    }
    float s = tanh_fast(d0 + bl0) * q0 + tanh_fast(d1 + bl1) * q1;
    #pragma unroll
    for (int off = 32; off > 0; off >>= 1) s += __shfl_down(s, off, 64);
    if (lane == 0) sc[r] = s + bb;
  }
}

__global__ __launch_bounds__(1024) void softmax_red(
    const float* __restrict__ sc, float* __restrict__ sred){
  const int t = threadIdx.x, lane = t & 63, wave = t >> 6;
  __shared__ float red[16];
  float m = -1e30f;
  for (int i = t; i < 8192; i += 1024) m = fmaxf(m, sc[i]);
  #pragma unroll
  for (int off = 32; off > 0; off >>= 1) m = fmaxf(m, __shfl_down(m, off, 64));
  if (lane == 0) red[wave] = m;
  __syncthreads();
  if (t == 0){
    float mm = red[0];
    for (int w = 1; w < 16; ++w) mm = fmaxf(mm, red[w]);
    red[0] = mm;
  }
  __syncthreads();
  const float bmax = red[0];
  __syncthreads();
  float s = 0.f;
  for (int i = t; i < 8192; i += 1024) s += __expf(sc[i] - bmax);
  #pragma unroll
  for (int off = 32; off > 0; off >>= 1) s += __shfl_down(s, off, 64);
  if (lane == 0) red[wave] = s;
  __syncthreads();
  if (t == 0){
    float ss = 0.f;
    for (int w = 0; w < 16; ++w) ss += red[w];
    sred[0] = bmax; sred[1] = ss;
  }
}

__global__ __launch_bounds__(256) void weighted_part(
    const float* __restrict__ sc, const float* __restrict__ sred,
    const float* __restrict__ Z, float* __restrict__ part){
  const int blk = blockIdx.x, t = threadIdx.x;
  const int o = t & 127, h = t >> 7;
  const float bmax = sred[0], inv = 1.f / sred[1];
  float acc = 0.f;
  const int i0 = blk * 128;
  for (int i = i0 + h; i < i0 + 128; i += 2){
    float w = __expf(sc[i] - bmax) * inv;
    acc += w * Z[(size_t)i * 128 + o];
  }
  __shared__ float l[256];
  l[t] = acc;
  __syncthreads();
  if (h == 0) part[blk * 128 + o] = l[o] + l[o + 128];
}

__global__ __launch_bounds__(128) void final_red(
    const float* __restrict__ part, float* __restrict__ out){
  const int o = threadIdx.x;
  float s = 0.f;
  for (int b = 0; b < 64; ++b) s += part[b * 128 + o];
  out[o] = s;
}

// ---------------------------------------------------------------------------
extern "C" void kernel_launch(void* const* d_in, const int* in_sizes, int n_in,
                              void* d_out, int out_size, void* d_ws, size_t ws_size,
                              hipStream_t stream){
  const float* x  = (const float*)d_in[0];
  const float* A  = (const float*)d_in[1];
  const float* W1 = (const float*)d_in[2];
  const float* W2 = (const float*)d_in[3];
  const float* W3 = (const float*)d_in[4];
  const float* Wl = (const float*)d_in[5];
  const float* bl = (const float*)d_in[6];
  const float* q  = (const float*)d_in[7];
  const float* b  = (const float*)d_in[8];
  float* out = (float*)d_out;
  char* ws = (char*)d_ws;

  u16*   AB   = (u16*)(ws);                      // 128 MiB, tiled
  float* DS   = (float*)(ws + 134217728);        // 32 KiB
  u16*   VT   = (u16*)(ws + 134250496);          // 4 MiB, tiled
  u16*   HB   = (u16*)(ws + 138444800);          // 4 MiB, tiled
  float* SC   = (float*)(ws + 142639104);        // 8192 f32 scores
  float* SP   = (float*)(ws + 142671872);        // 64*128 f32
  float* SRED = (float*)(ws + 142704640);        // {max, sumexp}
  u16*   W2T  = (u16*)(ws + 142705664);          // 128 KiB tiled W2
  u16*   W3T  = (u16*)(ws + 142836736);          // 64 KiB tiled W3
  u16*   W1T  = (u16*)(ws + 142902272);          // 64 KiB tiled W1
  u16*   XT   = (u16*)(ws + 142967808);          // 2 MiB tiled x

  rowsum_tileA<<<256, 1024, 0, stream>>>(A, AB, DS);
  prep_x<<<256, 1024, 0, stream>>>(x, XT);
  prep_w<<<256, 64, 0, stream>>>(W1, W2, W3, W1T, W2T, W3T);
  // layer 1 (KT = 128/16 = 8)
  small_mfma<256, 8><<<256, 256, 0, stream>>>(XT, W1T, DS, VT);
  gemm_rt<<<512, 256, 0, stream>>>(AB, VT, DS, HB);
  // layer 2
  small_mfma<256, 16><<<256, 256, 0, stream>>>(HB, W2T, DS, VT);
  gemm_rt<<<512, 256, 0, stream>>>(AB, VT, DS, HB);
  // layer 3 -> z_context f32 straight into d_out
  small_mfma<128, 16><<<256, 256, 0, stream>>>(HB, W3T, DS, VT);
  gemm_rt128<<<512, 256, 0, stream>>>(AB, VT, DS, out);
  // attention pooling
  attn_scores<<<512, 256, 0, stream>>>(out, Wl, bl, q, b, SC);
  softmax_red<<<1, 1024, 0, stream>>>(SC, SRED);
  weighted_part<<<64, 256, 0, stream>>>(SC, SRED, out, SP);
  final_red<<<1, 128, 0, stream>>>(SP, out + 8192 * 128);
}